// Round 1
// baseline (330.395 us; speedup 1.0000x reference)
//
#include <hip/hip_runtime.h>

// IF spiking neuron, T=8 timesteps over (B=32, T=8, C*H*W=200704) fp32.
// Pure streaming memory-bound: 205 MB in + 205 MB out.
// One thread per float4 of neurons; sequential walk over t with stride CHW.

#define CHW_VEC 50176   // 64*56*56 / 4
#define TSTEPS 8
#define NBATCH 32

__global__ __launch_bounds__(256) void IF_33122787787165_kernel(
    const float4* __restrict__ x, float4* __restrict__ out) {
    const int i = blockIdx.x * 256 + threadIdx.x;   // [0, 50176) vec4 index in CHW
    const int b = blockIdx.y;                        // [0, 32)
    const long long base = (long long)b * TSTEPS * CHW_VEC + i;

    float4 mem = make_float4(0.f, 0.f, 0.f, 0.f);
#pragma unroll
    for (int t = 0; t < TSTEPS; ++t) {
        const float4 xt = x[base + (long long)t * CHW_VEC];
        mem.x += xt.x;
        mem.y += xt.y;
        mem.z += xt.z;
        mem.w += xt.w;
        float4 s;
        s.x = (mem.x > 1.0f) ? 1.0f : 0.0f;
        s.y = (mem.y > 1.0f) ? 1.0f : 0.0f;
        s.z = (mem.z > 1.0f) ? 1.0f : 0.0f;
        s.w = (mem.w > 1.0f) ? 1.0f : 0.0f;
        // hard reset on spike
        mem.x = (mem.x > 1.0f) ? 0.0f : mem.x;
        mem.y = (mem.y > 1.0f) ? 0.0f : mem.y;
        mem.z = (mem.z > 1.0f) ? 0.0f : mem.z;
        mem.w = (mem.w > 1.0f) ? 0.0f : mem.w;
        out[base + (long long)t * CHW_VEC] = s;
    }
}

extern "C" void kernel_launch(void* const* d_in, const int* in_sizes, int n_in,
                              void* d_out, int out_size, void* d_ws, size_t ws_size,
                              hipStream_t stream) {
    const float4* x = (const float4*)d_in[0];
    float4* out = (float4*)d_out;
    dim3 grid(CHW_VEC / 256, NBATCH);  // 196 x 32 blocks
    IF_33122787787165_kernel<<<grid, 256, 0, stream>>>(x, out);
}

// Round 3
// 324.966 us; speedup vs baseline: 1.0167x; 1.0167x over previous
//
#include <hip/hip_runtime.h>

// IF spiking neuron, T=8 over (B=32, T=8, CHW=200704) fp32. Streaming,
// zero-reuse: 205 MB in + 205 MB out. Nontemporal accesses bypass L2
// (no reuse to cache); 2 float4/thread doubles loads-in-flight.
// Use clang native vector type: __builtin_nontemporal_* rejects HIP float4.

typedef float v4f __attribute__((ext_vector_type(4)));

#define CHW_VEC 50176   // 64*56*56 / 4
#define TSTEPS 8
#define NBATCH 32
#define BLK 256
#define VPT 2           // vec4s per thread

__global__ __launch_bounds__(BLK) void IF_33122787787165_kernel(
    const v4f* __restrict__ x, v4f* __restrict__ out) {
    const int i0 = blockIdx.x * (BLK * VPT) + threadIdx.x;  // vec4 index, lane-contiguous
    const int b = blockIdx.y;
    const long long base = (long long)b * TSTEPS * CHW_VEC + i0;

    v4f mem[VPT];
#pragma unroll
    for (int v = 0; v < VPT; ++v) mem[v] = (v4f)(0.0f);

#pragma unroll
    for (int t = 0; t < TSTEPS; ++t) {
        v4f xt[VPT];
#pragma unroll
        for (int v = 0; v < VPT; ++v)
            xt[v] = __builtin_nontemporal_load(&x[base + (long long)t * CHW_VEC + v * BLK]);
#pragma unroll
        for (int v = 0; v < VPT; ++v) {
            v4f m = mem[v] + xt[v];
            v4f s;
            s.x = (m.x > 1.0f) ? 1.0f : 0.0f;
            s.y = (m.y > 1.0f) ? 1.0f : 0.0f;
            s.z = (m.z > 1.0f) ? 1.0f : 0.0f;
            s.w = (m.w > 1.0f) ? 1.0f : 0.0f;
            m.x = (m.x > 1.0f) ? 0.0f : m.x;
            m.y = (m.y > 1.0f) ? 0.0f : m.y;
            m.z = (m.z > 1.0f) ? 0.0f : m.z;
            m.w = (m.w > 1.0f) ? 0.0f : m.w;
            mem[v] = m;
            __builtin_nontemporal_store(s, &out[base + (long long)t * CHW_VEC + v * BLK]);
        }
    }
}

extern "C" void kernel_launch(void* const* d_in, const int* in_sizes, int n_in,
                              void* d_out, int out_size, void* d_ws, size_t ws_size,
                              hipStream_t stream) {
    const v4f* x = (const v4f*)d_in[0];
    v4f* out = (v4f*)d_out;
    dim3 grid(CHW_VEC / (BLK * VPT), NBATCH);  // 98 x 32 blocks
    IF_33122787787165_kernel<<<grid, BLK, 0, stream>>>(x, out);
}

// Round 4
// 322.293 us; speedup vs baseline: 1.0251x; 1.0083x over previous
//
#include <hip/hip_runtime.h>

// IF spiking neuron, T=8 over (B=32, T=8, CHW=200704) fp32. Streaming,
// zero-reuse: 205 MB in + 205 MB out -> pure HBM roofline.
// Structure: issue ALL 16 nt loads first (independent addresses), then the
// 8-step membrane recurrence + 16 nt stores. Decouples read burst from
// write burst so load waits never count stores. 32-bit offsets (<2.1GB).

typedef float v4f __attribute__((ext_vector_type(4)));

#define CHW_VEC 50176   // 64*56*56 / 4
#define TSTEPS 8
#define NBATCH 32
#define BLK 256
#define VPT 2           // vec4s per thread

__global__ __launch_bounds__(BLK) void IF_33122787787165_kernel(
    const v4f* __restrict__ x, v4f* __restrict__ out) {
    const unsigned i0 = blockIdx.x * (BLK * VPT) + threadIdx.x;  // vec4 idx in CHW
    const unsigned b = blockIdx.y;
    const unsigned base = b * (TSTEPS * CHW_VEC) + i0;           // max ~51.4M vec4 < 2^31

    // Phase 1: burst-issue all loads (8 t-steps x VPT), all independent.
    v4f xt[TSTEPS][VPT];
#pragma unroll
    for (int t = 0; t < TSTEPS; ++t)
#pragma unroll
        for (int v = 0; v < VPT; ++v)
            xt[t][v] = __builtin_nontemporal_load(&x[base + (unsigned)t * CHW_VEC + v * BLK]);

    // Phase 2: recurrence + stores.
    v4f mem[VPT];
#pragma unroll
    for (int v = 0; v < VPT; ++v) mem[v] = (v4f)(0.0f);

#pragma unroll
    for (int t = 0; t < TSTEPS; ++t) {
#pragma unroll
        for (int v = 0; v < VPT; ++v) {
            v4f m = mem[v] + xt[t][v];
            v4f s;
            s.x = (m.x > 1.0f) ? 1.0f : 0.0f;
            s.y = (m.y > 1.0f) ? 1.0f : 0.0f;
            s.z = (m.z > 1.0f) ? 1.0f : 0.0f;
            s.w = (m.w > 1.0f) ? 1.0f : 0.0f;
            m.x = (m.x > 1.0f) ? 0.0f : m.x;
            m.y = (m.y > 1.0f) ? 0.0f : m.y;
            m.z = (m.z > 1.0f) ? 0.0f : m.z;
            m.w = (m.w > 1.0f) ? 0.0f : m.w;
            mem[v] = m;
            __builtin_nontemporal_store(s, &out[base + (unsigned)t * CHW_VEC + v * BLK]);
        }
    }
}

extern "C" void kernel_launch(void* const* d_in, const int* in_sizes, int n_in,
                              void* d_out, int out_size, void* d_ws, size_t ws_size,
                              hipStream_t stream) {
    const v4f* x = (const v4f*)d_in[0];
    v4f* out = (v4f*)d_out;
    dim3 grid(CHW_VEC / (BLK * VPT), NBATCH);  // 98 x 32 blocks
    IF_33122787787165_kernel<<<grid, BLK, 0, stream>>>(x, out);
}